// Round 1
// baseline (102.158 us; speedup 1.0000x reference)
//
#include <hip/hip_runtime.h>

#define N_MICS  192
#define OVERLAP 1024
#define WINDOW  524288
#define ROWLEN  (OVERLAP + WINDOW)

__global__ __launch_bounds__(256) void tdbf_kernel(
    const float* __restrict__ pos,
    const float* __restrict__ mic_pos,
    const float* __restrict__ buf,
    float* __restrict__ out)
{
    __shared__ float s_dist[N_MICS];
    __shared__ int   s_di[N_MICS];
    __shared__ float s_df[N_MICS];

    const int tid = threadIdx.x;

    // ---- per-block delay computation (exact f32 replication of numpy) ----
    if (tid < N_MICS) {
        float dx = __fsub_rn(pos[0], mic_pos[tid * 3 + 0]);
        float dy = __fsub_rn(pos[1], mic_pos[tid * 3 + 1]);
        float dz = __fsub_rn(pos[2], mic_pos[tid * 3 + 2]);
        // sum order: (dx*dx + dy*dy) + dz*dz, no FMA contraction
        float ss = __fadd_rn(__fadd_rn(__fmul_rn(dx, dx), __fmul_rn(dy, dy)),
                             __fmul_rn(dz, dz));
        s_dist[tid] = __fsqrt_rn(ss);
    }
    __syncthreads();
    if (tid < N_MICS) {
        float mx = s_dist[0];
        for (int i = 1; i < N_MICS; ++i) mx = fmaxf(mx, s_dist[i]);
        float dd = __fsub_rn(s_dist[tid], mx);              // <= 0
        // delay = ((-dd / 343000) * 768000) / 16   (numpy op order, f32)
        float delay = __fmul_rn(
                          __fmul_rn(__fdiv_rn(-dd, 343000.0f), 768000.0f),
                          0.0625f);                         // /16 is exact
        int di = (int)delay;                                // trunc, delay >= 0
        s_di[tid] = di;
        s_df[tid] = __fsub_rn(delay, (float)di);
    }
    __syncthreads();

    // ---- main beamform: one output sample per thread, loop over mics ----
    const int t = blockIdx.x * 256 + tid;                   // grid sized exactly
    float acc = 0.0f;
    #pragma unroll 8
    for (int m = 0; m < N_MICS; ++m) {
        const int   di = s_di[m];
        const float f  = s_df[m];
        const float* row = buf + (size_t)m * ROWLEN + (size_t)(t + OVERLAP - di);
        float v1 = row[0];
        float v2 = row[-1];
        acc += v1 * (1.0f - f) + v2 * f;
    }
    out[t] = __fdiv_rn(acc, (float)N_MICS);
}

extern "C" void kernel_launch(void* const* d_in, const int* in_sizes, int n_in,
                              void* d_out, int out_size, void* d_ws, size_t ws_size,
                              hipStream_t stream) {
    const float* pos     = (const float*)d_in[0];
    const float* mic_pos = (const float*)d_in[1];
    const float* buf     = (const float*)d_in[2];
    float* out           = (float*)d_out;

    dim3 grid(WINDOW / 256);
    dim3 block(256);
    tdbf_kernel<<<grid, block, 0, stream>>>(pos, mic_pos, buf, out);
}

// Round 2
// 77.553 us; speedup vs baseline: 1.3173x; 1.3173x over previous
//
#include <hip/hip_runtime.h>

#define N_MICS  192
#define OVERLAP 1024
#define WINDOW  524288
#define ROWLEN  (OVERLAP + WINDOW)
#define SPT     4                      // samples per thread
#define BLK     256

__global__ __launch_bounds__(BLK) void tdbf_kernel(
    const float* __restrict__ pos,
    const float* __restrict__ mic_pos,
    const float* __restrict__ buf,
    float* __restrict__ out)
{
    __shared__ float s_dist[N_MICS];
    __shared__ int   s_off[N_MICS];    // element offset: m*ROWLEN + OVERLAP - di[m]
    __shared__ float s_df[N_MICS];

    const int tid = threadIdx.x;

    // ---- per-block delay computation (exact f32 replication of numpy) ----
    if (tid < N_MICS) {
        float dx = __fsub_rn(pos[0], mic_pos[tid * 3 + 0]);
        float dy = __fsub_rn(pos[1], mic_pos[tid * 3 + 1]);
        float dz = __fsub_rn(pos[2], mic_pos[tid * 3 + 2]);
        float ss = __fadd_rn(__fadd_rn(__fmul_rn(dx, dx), __fmul_rn(dy, dy)),
                             __fmul_rn(dz, dz));
        s_dist[tid] = __fsqrt_rn(ss);
    }
    __syncthreads();
    if (tid < N_MICS) {
        float mx = s_dist[0];
        for (int i = 1; i < N_MICS; ++i) mx = fmaxf(mx, s_dist[i]);
        float dd = __fsub_rn(s_dist[tid], mx);              // <= 0
        float delay = __fmul_rn(
                          __fmul_rn(__fdiv_rn(-dd, 343000.0f), 768000.0f),
                          0.0625f);                         // /16 exact
        int di = (int)delay;                                // trunc, delay >= 0
        s_off[tid] = tid * ROWLEN + OVERLAP - di;
        s_df[tid]  = __fsub_rn(delay, (float)di);
    }
    __syncthreads();

    // ---- main beamform: 4 consecutive output samples per thread ----
    const int t4 = (blockIdx.x * BLK + tid) * SPT;
    float a0 = 0.0f, a1 = 0.0f, a2 = 0.0f, a3 = 0.0f;

    #pragma unroll 6
    for (int m = 0; m < N_MICS; ++m) {
        // wave-uniform values -> SGPRs so loads use saddr + shared voffset
        const int   off = __builtin_amdgcn_readfirstlane(s_off[m]);
        const float f   = __uint_as_float(
                              __builtin_amdgcn_readfirstlane(__float_as_uint(s_df[m])));
        const float* p  = buf + off + t4;
        const float vm1 = p[-1];
        const float v0  = p[0];
        const float v1  = p[1];
        const float v2  = p[2];
        const float v3  = p[3];
        const float g   = 1.0f - f;
        // delayed[t] = v1[t]*(1-f) + v1[t-1]*f
        a0 = fmaf(v0, g, fmaf(vm1, f, a0));
        a1 = fmaf(v1, g, fmaf(v0,  f, a1));
        a2 = fmaf(v2, g, fmaf(v1,  f, a2));
        a3 = fmaf(v3, g, fmaf(v2,  f, a3));
    }

    const float inv = 1.0f / (float)N_MICS;
    float4 o;
    o.x = a0 * inv; o.y = a1 * inv; o.z = a2 * inv; o.w = a3 * inv;
    *reinterpret_cast<float4*>(out + t4) = o;   // t4 % 4 == 0 -> 16B aligned
}

extern "C" void kernel_launch(void* const* d_in, const int* in_sizes, int n_in,
                              void* d_out, int out_size, void* d_ws, size_t ws_size,
                              hipStream_t stream) {
    const float* pos     = (const float*)d_in[0];
    const float* mic_pos = (const float*)d_in[1];
    const float* buf     = (const float*)d_in[2];
    float* out           = (float*)d_out;

    dim3 grid(WINDOW / (BLK * SPT));   // 512 blocks
    dim3 block(BLK);
    tdbf_kernel<<<grid, block, 0, stream>>>(pos, mic_pos, buf, out);
}